// Round 10
// baseline (228.599 us; speedup 1.0000x reference)
//
#include <hip/hip_runtime.h>

#define NQ 1024
#define NO 2048
#define LAT 128
#define CHUNK 32
#define NCHUNK (NO / CHUNK)          // 64
#define LDSTR 132   // padded LDS row stride (floats)
#define LOG2E 1.4426950408889634f
#define NEG_BIG -3.0e38f
#define MASK_THRESH -1.0e37f
#define PART_STRIDE 136   // 4 m + 4 lsum + 128 acc (floats per (slot,q))
#define SY_MAX 32

// ---------------------------------------------------------------------------
// value path: h_obs <- LayerNorm(h_obs) @ Wv + bv (in place).
// 2 obs x 128 threads; k-chain split into 4 accumulators (ILP 4).
// ---------------------------------------------------------------------------
__global__ __launch_bounds__(256) void gano_value(
    const float* __restrict__ ln_g,
    const float* __restrict__ ln_b,
    const float* __restrict__ Wv,
    const float* __restrict__ bv,
    float* __restrict__ h)
{
    __shared__ float hn[2][LAT];
    __shared__ float red[2][4];
    const int t = threadIdx.x;
    const int o = t >> 7;           // obs within block (0..1)
    const int d = t & 127;          // output dim
    const int ob = blockIdx.x * 2 + o;

    const float x = h[(size_t)ob*LAT + d];
    float s1 = x, s2 = x*x;
#pragma unroll
    for (int off = 32; off >= 1; off >>= 1) {
        s1 += __shfl_xor(s1, off);
        s2 += __shfl_xor(s2, off);
    }
    const int wv = (t >> 6) & 1;    // wave within obs
    if ((t & 63) == 0) { red[o][wv*2] = s1; red[o][wv*2+1] = s2; }
    __syncthreads();
    const float S1 = red[o][0] + red[o][2];
    const float S2 = red[o][1] + red[o][3];
    const float mean = S1 * (1.0f/LAT);
    const float var  = S2 * (1.0f/LAT) - mean*mean;
    const float rstd = rsqrtf(var + 1e-5f);
    hn[o][d] = (x - mean) * rstd * ln_g[d] + ln_b[d];
    __syncthreads();

    float a0 = bv[d], a1 = 0.f, a2 = 0.f, a3 = 0.f;
    const float* wc = Wv + d;
    const float* hh = hn[o];
#pragma unroll 8
    for (int kk = 0; kk < 32; ++kk) {
        a0 = fmaf(hh[kk],      wc[(size_t)(kk)*LAT],      a0);
        a1 = fmaf(hh[kk + 32], wc[(size_t)(kk + 32)*LAT], a1);
        a2 = fmaf(hh[kk + 64], wc[(size_t)(kk + 64)*LAT], a2);
        a3 = fmaf(hh[kk + 96], wc[(size_t)(kk + 96)*LAT], a3);
    }
    h[(size_t)ob*LAT + d] = (a0 + a1) + (a2 + a3);
}

// ---------------------------------------------------------------------------
// main, two-phase per chunk, CHUNK=32 with TWO pairs per phase-1 thread.
//  Phase 1: thread (qi,i) computes full 128-dim MLP logits for pairs
//   (q, oc=i) and (q, oc=i+16). The two chains are independent (ILP x2 at
//   the ds_read->FMA stalls) and SHARE the cc LDS read + the whole
//   W1[9]/W2 scalar stream (per-pair LDS/SMEM pressure ~halved vs R9).
//  Phase 2: dims [i*8,i*8+8); softmax over obs pairs (register diet, R9).
// LDS ~34 KB -> 4 blocks/CU = 16 waves/CU = the VGPR-allowed residency, so
// nothing is lost to the bigger tile; barriers per block halve.
// Plain __launch_bounds__(256): min-waves arg caps VGPR at 256/w (R7 spill).
// ---------------------------------------------------------------------------
__global__ __launch_bounds__(256) void gano_main(
    const float* __restrict__ v,          // h_obs buffer, now holding v
    const float* __restrict__ pos_obs,
    const float* __restrict__ pos_query,
    const int* __restrict__ obs_batch,
    const int* __restrict__ query_batch,
    const float* __restrict__ W1,
    const float* __restrict__ b1,
    const float* __restrict__ W2,
    const float* __restrict__ b2,
    float* __restrict__ ws,
    float* __restrict__ out,
    int SY)
{
    __shared__ __align__(16) float ld[CHUNK*LDSTR];   // d_o tile, padded  16.9 KB
    __shared__ __align__(16) float lcq[16*LDSTR];     // c_q, padded        8.4 KB
    __shared__ __align__(16) float lgt[16*4*CHUNK];   // logits [q][h][oc']   8 KB
    __shared__ float lpos[CHUNK*3];
    __shared__ int   lob[CHUNK];

    const int tid = threadIdx.x;
    const int i  = tid & 15;        // phase1: oc-low ; phase2: dim-slice
    const int qi = tid >> 4;        // query within block
    const int q  = blockIdx.x * 16 + qi;
    const int d0 = i * 8;           // phase-2 dims
    const int hstar = i >> 2;       // phase-2 head

    // ---- block-init: c_q into LDS (padded rows) ----
#pragma unroll
    for (int t2 = 0; t2 < 2; ++t2) {
        const int idx = tid + t2*256;
        const int row = idx >> 5;            // query 0..15
        const int g   = idx & 31;            // float4 group
        const int dd4 = g * 4;
        const int qq  = blockIdx.x * 16 + row;
        const float px = pos_query[qq*3+0];
        const float py = pos_query[qq*3+1];
        const float pz = pos_query[qq*3+2];
        float4 c = *(const float4*)(b1 + dd4);
        const float4 wx0 = *(const float4*)(W1 + 0*LAT + dd4);
        const float4 wx6 = *(const float4*)(W1 + 6*LAT + dd4);
        const float4 wy0 = *(const float4*)(W1 + 1*LAT + dd4);
        const float4 wy6 = *(const float4*)(W1 + 7*LAT + dd4);
        const float4 wz0 = *(const float4*)(W1 + 2*LAT + dd4);
        const float4 wz6 = *(const float4*)(W1 + 8*LAT + dd4);
        c.x = fmaf(px, wx0.x+wx6.x, fmaf(py, wy0.x+wy6.x, fmaf(pz, wz0.x+wz6.x, c.x)));
        c.y = fmaf(px, wx0.y+wx6.y, fmaf(py, wy0.y+wy6.y, fmaf(pz, wz0.y+wz6.y, c.y)));
        c.z = fmaf(px, wx0.z+wx6.z, fmaf(py, wy0.z+wy6.z, fmaf(pz, wz0.z+wz6.z, c.z)));
        c.w = fmaf(px, wx0.w+wx6.w, fmaf(py, wy0.w+wy6.w, fmaf(pz, wz0.w+wz6.w, c.w)));
        *(float4*)(lcq + row*LDSTR + dd4) = c;
    }

    const float pqx = pos_query[q*3+0];
    const float pqy = pos_query[q*3+1];
    const float pqz = pos_query[q*3+2];
    const int   qb  = query_batch[q];
    const float b2l0 = b2[0]*LOG2E, b2l1 = b2[1]*LOG2E;
    const float b2l2 = b2[2]*LOG2E, b2l3 = b2[3]*LOG2E;

    float4 accA = make_float4(0.f,0.f,0.f,0.f);
    float4 accB = make_float4(0.f,0.f,0.f,0.f);
    float m = NEG_BIG, lsum = 0.f;

    for (int cb = blockIdx.y; cb < NCHUNK; cb += SY) {
        const int o0 = cb * CHUNK;
        __syncthreads();   // prior phase-2 lgt reads done; lcq ready (1st)

        // ---- stage d_o (padded rows; W1 rows 3..8 from L1) ----
#pragma unroll
        for (int t2 = 0; t2 < 4; ++t2) {
            const int idx = tid + t2*256;
            const int oo = idx >> 5;           // obs within chunk
            const int g  = idx & 31;           // float4 group
            const int d4 = g * 4;
            const float* po = pos_obs + (size_t)(o0 + oo)*3;
            const float px = po[0], py = po[1], pz = po[2];
            const float4 w3 = *(const float4*)(W1 + 3*LAT + d4);
            const float4 w4 = *(const float4*)(W1 + 4*LAT + d4);
            const float4 w5 = *(const float4*)(W1 + 5*LAT + d4);
            const float4 w6 = *(const float4*)(W1 + 6*LAT + d4);
            const float4 w7 = *(const float4*)(W1 + 7*LAT + d4);
            const float4 w8 = *(const float4*)(W1 + 8*LAT + d4);
            float4 r;
            r.x = fmaf(px, w3.x-w6.x, fmaf(py, w4.x-w7.x, pz*(w5.x-w8.x)));
            r.y = fmaf(px, w3.y-w6.y, fmaf(py, w4.y-w7.y, pz*(w5.y-w8.y)));
            r.z = fmaf(px, w3.z-w6.z, fmaf(py, w4.z-w7.z, pz*(w5.z-w8.z)));
            r.w = fmaf(px, w3.w-w6.w, fmaf(py, w4.w-w7.w, pz*(w5.w-w8.w)));
            *(float4*)(ld + oo*LDSTR + d4) = r;
        }
        for (int idx = tid; idx < CHUNK*3; idx += 256) lpos[idx] = pos_obs[o0*3 + idx];
        for (int idx = tid; idx < CHUNK;   idx += 256) lob[idx]  = obs_batch[o0 + idx];
        __syncthreads();

        // ---- phase 1: two full logits per thread (independent chains) ----
        {
            const int ocA = i, ocB = i + 16;
            const float dxA = pqx - lpos[ocA*3+0];
            const float dyA = pqy - lpos[ocA*3+1];
            const float dzA = pqz - lpos[ocA*3+2];
            const float dxB = pqx - lpos[ocB*3+0];
            const float dyB = pqy - lpos[ocB*3+1];
            const float dzB = pqz - lpos[ocB*3+2];
            const float distA = sqrtf(dxA*dxA + dyA*dyA + dzA*dzA);
            const float distB = sqrtf(dxB*dxB + dyB*dyB + dzB*dzB);
            const int mbA = (lob[ocA] == qb);
            const int mbB = (lob[ocB] == qb);

            float lgA0 = 0.f, lgA1 = 0.f, lgA2 = 0.f, lgA3 = 0.f;
            float lgB0 = 0.f, lgB1 = 0.f, lgB2 = 0.f, lgB3 = 0.f;
            const float* ldrA = ld + ocA*LDSTR;
            const float* ldrB = ld + ocB*LDSTR;
            const float* lcr  = lcq + qi*LDSTR;
#pragma unroll 2
            for (int j = 0; j < 32; ++j) {
                const float4 dA = *(const float4*)(ldrA + j*4);
                const float4 dB = *(const float4*)(ldrB + j*4);
                const float4 cc = *(const float4*)(lcr + j*4);
                const float4 wd = *(const float4*)(W1 + 9*LAT + j*4);   // uniform -> s_load
                const float4 w2a = *(const float4*)(W2 + (j*4+0)*4);    // uniform
                const float4 w2b = *(const float4*)(W2 + (j*4+1)*4);
                const float4 w2c = *(const float4*)(W2 + (j*4+2)*4);
                const float4 w2d = *(const float4*)(W2 + (j*4+3)*4);
                const float hA0 = fmaxf(fmaf(wd.x, distA, cc.x + dA.x), 0.f);
                const float hA1 = fmaxf(fmaf(wd.y, distA, cc.y + dA.y), 0.f);
                const float hA2 = fmaxf(fmaf(wd.z, distA, cc.z + dA.z), 0.f);
                const float hA3 = fmaxf(fmaf(wd.w, distA, cc.w + dA.w), 0.f);
                const float hB0 = fmaxf(fmaf(wd.x, distB, cc.x + dB.x), 0.f);
                const float hB1 = fmaxf(fmaf(wd.y, distB, cc.y + dB.y), 0.f);
                const float hB2 = fmaxf(fmaf(wd.z, distB, cc.z + dB.z), 0.f);
                const float hB3 = fmaxf(fmaf(wd.w, distB, cc.w + dB.w), 0.f);
                lgA0 = fmaf(hA0, w2a.x, lgA0); lgA1 = fmaf(hA0, w2a.y, lgA1);
                lgA2 = fmaf(hA0, w2a.z, lgA2); lgA3 = fmaf(hA0, w2a.w, lgA3);
                lgB0 = fmaf(hB0, w2a.x, lgB0); lgB1 = fmaf(hB0, w2a.y, lgB1);
                lgB2 = fmaf(hB0, w2a.z, lgB2); lgB3 = fmaf(hB0, w2a.w, lgB3);
                lgA0 = fmaf(hA1, w2b.x, lgA0); lgA1 = fmaf(hA1, w2b.y, lgA1);
                lgA2 = fmaf(hA1, w2b.z, lgA2); lgA3 = fmaf(hA1, w2b.w, lgA3);
                lgB0 = fmaf(hB1, w2b.x, lgB0); lgB1 = fmaf(hB1, w2b.y, lgB1);
                lgB2 = fmaf(hB1, w2b.z, lgB2); lgB3 = fmaf(hB1, w2b.w, lgB3);
                lgA0 = fmaf(hA2, w2c.x, lgA0); lgA1 = fmaf(hA2, w2c.y, lgA1);
                lgA2 = fmaf(hA2, w2c.z, lgA2); lgA3 = fmaf(hA2, w2c.w, lgA3);
                lgB0 = fmaf(hB2, w2c.x, lgB0); lgB1 = fmaf(hB2, w2c.y, lgB1);
                lgB2 = fmaf(hB2, w2c.z, lgB2); lgB3 = fmaf(hB2, w2c.w, lgB3);
                lgA0 = fmaf(hA3, w2d.x, lgA0); lgA1 = fmaf(hA3, w2d.y, lgA1);
                lgA2 = fmaf(hA3, w2d.z, lgA2); lgA3 = fmaf(hA3, w2d.w, lgA3);
                lgB0 = fmaf(hB3, w2d.x, lgB0); lgB1 = fmaf(hB3, w2d.y, lgB1);
                lgB2 = fmaf(hB3, w2d.z, lgB2); lgB3 = fmaf(hB3, w2d.w, lgB3);
            }
            // log2-domain, fold b2, mask; store at 4-rotated columns
            const int ocrA = (ocA + 4*qi) & 31;
            const int ocrB = (ocB + 4*qi) & 31;
            float* lrow = lgt + (qi*4)*CHUNK;
            lrow[0*CHUNK + ocrA] = mbA ? fmaf(lgA0, LOG2E, b2l0) : NEG_BIG;
            lrow[1*CHUNK + ocrA] = mbA ? fmaf(lgA1, LOG2E, b2l1) : NEG_BIG;
            lrow[2*CHUNK + ocrA] = mbA ? fmaf(lgA2, LOG2E, b2l2) : NEG_BIG;
            lrow[3*CHUNK + ocrA] = mbA ? fmaf(lgA3, LOG2E, b2l3) : NEG_BIG;
            lrow[0*CHUNK + ocrB] = mbB ? fmaf(lgB0, LOG2E, b2l0) : NEG_BIG;
            lrow[1*CHUNK + ocrB] = mbB ? fmaf(lgB1, LOG2E, b2l1) : NEG_BIG;
            lrow[2*CHUNK + ocrB] = mbB ? fmaf(lgB2, LOG2E, b2l2) : NEG_BIG;
            lrow[3*CHUNK + ocrB] = mbB ? fmaf(lgB3, LOG2E, b2l3) : NEG_BIG;
        }
        __syncthreads();

        // ---- phase 2: softmax over obs pairs + aggregation ----
        {
            const float* rowp = lgt + (qi*4 + hstar)*CHUNK;
#pragma unroll
            for (int g = 0; g < 8; ++g) {
                // float4 = logits of logical obs g*4..g*4+3
                const float4 t4 = *(const float4*)(rowp + ((g + qi) & 7) * 4);
#pragma unroll
                for (int pr = 0; pr < 2; ++pr) {
                    const float l0 = pr ? t4.z : t4.x;
                    const float l1 = pr ? t4.w : t4.y;
                    const float mn = fmaxf(m, fmaxf(l0, l1));
                    const float alpha = exp2f(m - mn);
                    const float p0 = (l0 > MASK_THRESH) ? exp2f(l0 - mn) : 0.f;
                    const float p1 = (l1 > MASK_THRESH) ? exp2f(l1 - mn) : 0.f;
                    lsum = fmaf(lsum, alpha, p0 + p1);
                    m = mn;

                    const float* vp = v + (size_t)(o0 + g*4 + pr*2)*LAT + d0;
                    const float4 v0A = *(const float4*)(vp);
                    const float4 v0B = *(const float4*)(vp + 4);
                    const float4 v1A = *(const float4*)(vp + LAT);
                    const float4 v1B = *(const float4*)(vp + LAT + 4);
                    accA.x = fmaf(accA.x, alpha, fmaf(p0, v0A.x, p1*v1A.x));
                    accA.y = fmaf(accA.y, alpha, fmaf(p0, v0A.y, p1*v1A.y));
                    accA.z = fmaf(accA.z, alpha, fmaf(p0, v0A.z, p1*v1A.z));
                    accA.w = fmaf(accA.w, alpha, fmaf(p0, v0A.w, p1*v1A.w));
                    accB.x = fmaf(accB.x, alpha, fmaf(p0, v0B.x, p1*v1B.x));
                    accB.y = fmaf(accB.y, alpha, fmaf(p0, v0B.y, p1*v1B.y));
                    accB.z = fmaf(accB.z, alpha, fmaf(p0, v0B.z, p1*v1B.z));
                    accB.w = fmaf(accB.w, alpha, fmaf(p0, v0B.w, p1*v1B.w));
                }
            }
        }
    }

    if (SY == 1) {
        const float inv = 1.0f / lsum;
        float* op = out + (size_t)q*LAT + d0;
        float4 rA, rB;
        rA.x = accA.x*inv; rA.y = accA.y*inv; rA.z = accA.z*inv; rA.w = accA.w*inv;
        rB.x = accB.x*inv; rB.y = accB.y*inv; rB.z = accB.z*inv; rB.w = accB.w*inv;
        *(float4*)op       = rA;
        *(float4*)(op + 4) = rB;
    } else {
        float* pp = ws + ((size_t)blockIdx.y * NQ + q) * PART_STRIDE;
        if ((i & 3) == 0) {          // one writer per head (redundant values identical)
            pp[hstar]     = m;
            pp[4 + hstar] = lsum;
        }
        *(float4*)(pp + 8 + d0)     = accA;
        *(float4*)(pp + 8 + d0 + 4) = accB;
    }
}

// ---------------------------------------------------------------------------
// combine: stage m/lsum in LDS; per-slot loads independent; 2 accumulators.
// ---------------------------------------------------------------------------
__global__ __launch_bounds__(128) void gano_combine(
    const float* __restrict__ ws, float* __restrict__ out, int SY)
{
    __shared__ float lm[SY_MAX*4];
    __shared__ float ll[SY_MAX*4];
    const int q = blockIdx.x;
    const int l = threadIdx.x;
    const int h = l >> 5;

    if (l < SY*4) {
        const int s = l >> 2, hh = l & 3;
        const float* pp = ws + ((size_t)s * NQ + q) * PART_STRIDE;
        lm[l] = pp[hh];
        ll[l] = pp[4 + hh];
    }
    __syncthreads();

    float M = NEG_BIG;
    for (int s = 0; s < SY; ++s) M = fmaxf(M, lm[s*4 + h]);

    float Ls = 0.f, A0 = 0.f, A1 = 0.f;
#pragma unroll 4
    for (int s = 0; s + 1 < SY; s += 2) {
        const float e0 = exp2f(lm[s*4 + h] - M);
        const float e1 = exp2f(lm[(s+1)*4 + h] - M);
        Ls = fmaf(ll[s*4 + h], e0, fmaf(ll[(s+1)*4 + h], e1, Ls));
        A0 = fmaf(ws[((size_t)s     * NQ + q) * PART_STRIDE + 8 + l], e0, A0);
        A1 = fmaf(ws[((size_t)(s+1) * NQ + q) * PART_STRIDE + 8 + l], e1, A1);
    }
    if (SY & 1) {
        const int s = SY - 1;
        const float e0 = exp2f(lm[s*4 + h] - M);
        Ls = fmaf(ll[s*4 + h], e0, Ls);
        A0 = fmaf(ws[((size_t)s * NQ + q) * PART_STRIDE + 8 + l], e0, A0);
    }
    out[(size_t)q*LAT + l] = (A0 + A1) / Ls;
}

// ---------------------------------------------------------------------------
extern "C" void kernel_launch(void* const* d_in, const int* in_sizes, int n_in,
                              void* d_out, int out_size, void* d_ws, size_t ws_size,
                              hipStream_t stream) {
    (void)in_sizes; (void)n_in; (void)out_size;
    float*       h_obs     = (float*)d_in[0];        // mutated in place -> v
    const float* pos_obs   = (const float*)d_in[1];
    const float* pos_query = (const float*)d_in[2];
    const int*   obs_batch = (const int*)d_in[3];
    const int*   query_batch = (const int*)d_in[4];
    const float* W1 = (const float*)d_in[5];
    const float* b1 = (const float*)d_in[6];
    const float* W2 = (const float*)d_in[7];
    const float* b2 = (const float*)d_in[8];
    const float* ln_g = (const float*)d_in[9];
    const float* ln_b = (const float*)d_in[10];
    const float* Wv = (const float*)d_in[11];
    const float* bv = (const float*)d_in[12];
    float* ws  = (float*)d_ws;
    float* out = (float*)d_out;

    // split-O factor (NCHUNK=64 -> 2 chunks/block at SY=32).
    // Strictly bounded by what d_ws can hold (0 bytes touched @ SY=1).
    int SY = 1;
    const size_t per = (size_t)NQ * PART_STRIDE * sizeof(float);
    if (ws && ws_size >= 2*per) {
        size_t s = ws_size / per;
        SY = (int)(s < SY_MAX ? s : SY_MAX);
    }

    gano_value<<<NO/2, 256, 0, stream>>>(ln_g, ln_b, Wv, bv, h_obs);
    gano_main<<<dim3(NQ/16, SY), 256, 0, stream>>>(h_obs, pos_obs, pos_query,
                                                   obs_batch, query_batch,
                                                   W1, b1, W2, b2, ws, out, SY);
    if (SY > 1)
        gano_combine<<<NQ, 128, 0, stream>>>(ws, out, SY);
}